// Round 5
// baseline (6922.722 us; speedup 1.0000x reference)
//
#include <hip/hip_runtime.h>
#include <stdint.h>

typedef _Float16 f16;
typedef __attribute__((ext_vector_type(8))) _Float16 f16x8;
typedef __attribute__((ext_vector_type(4))) _Float16 f16x4;
typedef __attribute__((ext_vector_type(4))) float f32x4;

// Tiled weight layout in ws (f16 elems), K-tile = 32, tiles n-major [n][32]:
// W1: 4  tiles of [512][32] @ WS_W1; W2: 16 tiles of [512][32] @ WS_W2;
// W3: 16 tiles of [256][32] @ WS_W3 (n>=251 zeroed).
#define WS_W1 0
#define WS_W2 65536
#define WS_W3 327680

__global__ __launch_bounds__(256) void convert_weights_k(
    const float* __restrict__ W1, const float* __restrict__ W2,
    const float* __restrict__ W3, f16* __restrict__ ws)
{
  int idx = blockIdx.x * 256 + threadIdx.x;
  if (idx < 65536) {
    int kt = idx >> 14, r = idx & 16383, n = r >> 5, kk = r & 31;
    ws[WS_W1 + idx] = (f16)W1[(kt * 32 + kk) * 512 + n];
  } else if (idx < 327680) {
    int i = idx - 65536;
    int kt = i >> 14, r = i & 16383, n = r >> 5, kk = r & 31;
    ws[WS_W2 + i] = (f16)W2[(kt * 32 + kk) * 512 + n];
  } else if (idx < 458752) {
    int i = idx - 327680;
    int kt = i >> 13, r = i & 8191, n = r >> 5, kk = r & 31;
    ws[WS_W3 + i] = (n < 251) ? (f16)W3[(kt * 32 + kk) * 251 + n] : (f16)0.0f;
  }
}

__device__ __forceinline__ void gld16(char* lds, const char* g) {
  __builtin_amdgcn_global_load_lds(
      (const __attribute__((address_space(1))) uint32_t*)g,
      (__attribute__((address_space(3))) uint32_t*)lds, 16, 0, 0);
}

__device__ __forceinline__ f16x8 lds_ld8(const char* base, int m, int strideB, int kb) {
  return *(const f16x8*)(base + m * strideB + (kb ^ ((m & 7) << 4)));
}

// --------------------------- GEMM building blocks ---------------------------
template<int NT>
__device__ __forceinline__ void mlp_stage(
    const f16* __restrict__ wsrc, int ktiles, int tileB,
    char* slot0, char* slot1,
    const char* __restrict__ src, int srcStride,
    f32x4 acc[4][NT], int w, int lane, int l15, int lh)
{
  const char* gsrc = (const char*)wsrc + w * (NT * 1024) + lane * 16;
  #pragma unroll
  for (int r = 0; r < NT; ++r) gld16(slot0 + r * 1024, gsrc + r * 1024);
  #pragma unroll 1
  for (int kt = 0; kt < ktiles; ++kt) {
    char* cur = (kt & 1) ? slot1 : slot0;
    char* nxt = (kt & 1) ? slot0 : slot1;
    if (kt + 1 < ktiles) {
      const char* g = gsrc + (size_t)(kt + 1) * tileB;
      __builtin_amdgcn_sched_barrier(0);
      #pragma unroll
      for (int r = 0; r < NT; ++r) gld16(nxt + r * 1024, g + r * 1024);
      asm volatile("s_waitcnt vmcnt(%0)" :: "n"(NT) : "memory");
    } else {
      asm volatile("s_waitcnt vmcnt(0)" ::: "memory");
    }
    __builtin_amdgcn_sched_barrier(0);
    f16x8 a[NT];
    #pragma unroll
    for (int nt = 0; nt < NT; ++nt)
      a[nt] = *(const f16x8*)(cur + (nt * 16 + l15) * 64 + lh * 16);
    __builtin_amdgcn_s_setprio(1);
    #pragma unroll
    for (int mh = 0; mh < 4; ++mh) {
      f16x8 b = lds_ld8(src, mh * 16 + l15, srcStride, kt * 64 + lh * 16);
      #pragma unroll
      for (int nt = 0; nt < NT; ++nt)
        acc[mh][nt] = __builtin_amdgcn_mfma_f32_16x16x32_f16(a[nt], b, acc[mh][nt], 0, 0, 0);
    }
    __builtin_amdgcn_s_setprio(0);
  }
}

template<int NT>
__device__ __forceinline__ void store_act(
    f32x4 acc[4][NT], char* hbuf, const float* __restrict__ bias,
    int w, int l15, int lh)
{
  #pragma unroll
  for (int nt = 0; nt < NT; ++nt) {
    int ncol = w * (NT * 16) + nt * 16 + lh * 4;
    f32x4 bv = *(const f32x4*)(bias + ncol);
    #pragma unroll
    for (int mh = 0; mh < 4; ++mh) {
      int m = mh * 16 + l15;
      f16x4 hv;
      #pragma unroll
      for (int r = 0; r < 4; ++r) {
        float v = acc[mh][nt][r] + bv[r];
        hv[r] = (f16)(v > 0.f ? v : 0.01f * v);
      }
      *(f16x4*)(hbuf + m * 1024 + ((ncol * 2) ^ ((m & 7) << 4))) = hv;
    }
  }
}

__device__ __forceinline__ void store_logits(
    f32x4 acc[4][2], char* hbuf, int w, int l15, int lh)
{
  #pragma unroll
  for (int nt = 0; nt < 2; ++nt) {
    int ncol = w * 32 + nt * 16 + lh * 4;
    #pragma unroll
    for (int mh = 0; mh < 4; ++mh) {
      int m = mh * 16 + l15;
      *(f32x4*)(hbuf + m * 1024 + ((ncol * 4) ^ ((m & 7) << 4))) = acc[mh][nt];
    }
  }
}

__device__ __forceinline__ void stage_x(
    const float* __restrict__ obs, const float* __restrict__ act,
    char* xbuf, long rowBase, int tid)
{
  #pragma unroll
  for (int i = 0; i < 2; ++i) {
    int chunk = tid + i * 512;
    int m = chunk >> 4, g = chunk & 15;
    long row = rowBase + m;
    const float* src = (g < 12) ? (obs + row * 96 + g * 8)
                                : (act + row * 32 + (g - 12) * 8);
    float4 lo = ((const float4*)src)[0];
    float4 hi = ((const float4*)src)[1];
    f16x8 v;
    v[0] = (f16)lo.x; v[1] = (f16)lo.y; v[2] = (f16)lo.z; v[3] = (f16)lo.w;
    v[4] = (f16)hi.x; v[5] = (f16)hi.y; v[6] = (f16)hi.z; v[7] = (f16)hi.w;
    *(f16x8*)(xbuf + m * 256 + ((g * 16) ^ ((m & 7) << 4))) = v;
  }
}

// All 3 GEMM stages (round-4 structure, verbatim semantics)
__device__ __forceinline__ void run_gemms(
    const f16* __restrict__ ws, char* xbuf, char* hbuf,
    char* slot0, char* slot1,
    const float* __restrict__ bias1, const float* __restrict__ bias2,
    int w, int lane, int l15, int lh)
{
  {
    f32x4 acc[4][4];
    #pragma unroll
    for (int mh = 0; mh < 4; ++mh)
      #pragma unroll
      for (int nt = 0; nt < 4; ++nt) acc[mh][nt] = f32x4{0.f, 0.f, 0.f, 0.f};
    mlp_stage<4>(ws + WS_W1, 4, 32768, slot0, slot1, xbuf, 256, acc, w, lane, l15, lh);
    store_act<4>(acc, hbuf, bias1, w, l15, lh);
  }
  __syncthreads();
  {
    f32x4 acc[4][4];
    #pragma unroll
    for (int mh = 0; mh < 4; ++mh)
      #pragma unroll
      for (int nt = 0; nt < 4; ++nt) acc[mh][nt] = f32x4{0.f, 0.f, 0.f, 0.f};
    mlp_stage<4>(ws + WS_W2, 16, 32768, slot0, slot1, hbuf, 1024, acc, w, lane, l15, lh);
    __syncthreads();
    store_act<4>(acc, hbuf, bias2, w, l15, lh);
  }
  __syncthreads();
  {
    f32x4 acc[4][2];
    #pragma unroll
    for (int mh = 0; mh < 4; ++mh)
      #pragma unroll
      for (int nt = 0; nt < 2; ++nt) acc[mh][nt] = f32x4{0.f, 0.f, 0.f, 0.f};
    mlp_stage<2>(ws + WS_W3, 16, 16384, slot0, slot1, hbuf, 1024, acc, w, lane, l15, lh);
    __syncthreads();
    store_logits(acc, hbuf, w, l15, lh);
  }
}

// Epilogue: softmax + C51 projection (round-4 verbatim; out-store guarded)
__device__ __forceinline__ void run_epilogue(
    const char* lg, float* pr,
    const float* __restrict__ rewards, const float* __restrict__ bootstrap,
    const float* __restrict__ discount, const float* __restrict__ q_support,
    const float* __restrict__ bias3, float* __restrict__ out,
    long rowBase, int w, int lane, bool do_store)
{
  float zc[4], b3c[4];
  #pragma unroll
  for (int j = 0; j < 4; ++j) {
    int c = lane + j * 64;
    bool ok = c < 251;
    zc[j]  = ok ? q_support[c] : 0.f;
    b3c[j] = ok ? bias3[c] : 0.f;
  }
  #pragma unroll 1
  for (int i = 0; i < 8; ++i) {
    const int m = w * 8 + i;
    const long row = rowBase + m;
    float rw = rewards[row];
    float bd = __fmul_rn(bootstrap[row], discount[row]);
    #pragma unroll
    for (int j = 0; j < 4; ++j) pr[m * 256 + j * 64 + lane] = 0.f;
    float v[4];
    #pragma unroll
    for (int j = 0; j < 4; ++j) {
      int c = lane + j * 64;
      float t = *(const float*)(lg + m * 1024 + ((c * 4) ^ ((m & 7) << 4)));
      v[j] = (c < 251) ? t + b3c[j] : -3.0e38f;
    }
    float mx = fmaxf(fmaxf(v[0], v[1]), fmaxf(v[2], v[3]));
    #pragma unroll
    for (int s = 1; s < 64; s <<= 1) mx = fmaxf(mx, __shfl_xor(mx, s, 64));
    float e[4];
    float sum = 0.f;
    #pragma unroll
    for (int j = 0; j < 4; ++j) {
      int c = lane + j * 64;
      e[j] = (c < 251) ? __expf(v[j] - mx) : 0.f;
      sum += e[j];
    }
    #pragma unroll
    for (int s = 1; s < 64; s <<= 1) sum += __shfl_xor(sum, s, 64);
    float inv = 1.f / sum;
    #pragma unroll
    for (int j = 0; j < 4; ++j) {
      int c = lane + j * 64;
      if (c < 251) {
        float p = e[j] * inv;
        float tz = __fadd_rn(rw, __fmul_rn(bd, zc[j]));
        tz = fminf(fmaxf(tz, -100.f), 100.f);
        float b = __fdiv_rn(__fadd_rn(tz, 100.f), 0.8f);
        float lf = floorf(b), uf = ceilf(b);
        int li = (int)lf, ui = (int)uf;
        bool eq = (li == ui);
        int li2 = li - ((eq && (ui > 0)) ? 1 : 0);
        int ui2 = ui + ((eq && (li < 250)) ? 1 : 0);
        atomicAdd(&pr[m * 256 + li2], p * ((float)ui2 - b));
        atomicAdd(&pr[m * 256 + ui2], p * (b - (float)li2));
      }
    }
    if (do_store) {
      #pragma unroll
      for (int j = 0; j < 4; ++j) {
        int c = lane + j * 64;
        if (c < 251) out[row * 251 + c] = pr[m * 256 + c];
      }
    }
  }
}

// ------------------------------- kernels ------------------------------------
__global__ __launch_bounds__(512, 2) void fused_c51_k(
    const float* __restrict__ obs, const float* __restrict__ act,
    const float* __restrict__ rewards, const float* __restrict__ bootstrap,
    const float* __restrict__ discount, const float* __restrict__ q_support,
    const float* __restrict__ bias1, const float* __restrict__ bias2,
    const float* __restrict__ bias3, const f16* __restrict__ ws,
    float* __restrict__ out)
{
  extern __shared__ char smem[];
  char* hbuf = smem;
  char* xbuf = smem + 65536;
  char* wbase = smem + 81920;
  const int tid = threadIdx.x;
  const int lane = tid & 63;
  const int w = tid >> 6;
  const int l15 = lane & 15;
  const int lh = lane >> 4;
  const long rowBase = (long)blockIdx.x * 64;
  char* slot0 = wbase + w * 8192;
  char* slot1 = slot0 + 4096;

  stage_x(obs, act, xbuf, rowBase, tid);
  __syncthreads();
  run_gemms(ws, xbuf, hbuf, slot0, slot1, bias1, bias2, w, lane, l15, lh);
  __syncthreads();
  run_epilogue(hbuf, (float*)wbase, rewards, bootstrap, discount, q_support,
               bias3, out, rowBase, w, lane, true);
}

// ABLATION: GEMM path only, x16 reps. Writes liveness dwords into d_out
// (overwritten by fused_c51_k which runs last).
__global__ __launch_bounds__(512, 2) void abl_gemm_k(
    const float* __restrict__ obs, const float* __restrict__ act,
    const float* __restrict__ bias1, const float* __restrict__ bias2,
    const f16* __restrict__ ws, float* __restrict__ out)
{
  extern __shared__ char smem[];
  char* hbuf = smem;
  char* xbuf = smem + 65536;
  char* wbase = smem + 81920;
  const int tid = threadIdx.x;
  const int lane = tid & 63;
  const int w = tid >> 6;
  const int l15 = lane & 15;
  const int lh = lane >> 4;
  const long rowBase = (long)blockIdx.x * 64;
  char* slot0 = wbase + w * 8192;
  char* slot1 = slot0 + 4096;

  stage_x(obs, act, xbuf, rowBase, tid);
  __syncthreads();
  #pragma unroll 1
  for (int rep = 0; rep < 16; ++rep) {
    run_gemms(ws, xbuf, hbuf, slot0, slot1, bias1, bias2, w, lane, l15, lh);
    __syncthreads();
    asm volatile("" ::: "memory");
  }
  out[(long)blockIdx.x * 512 + tid] = *(const float*)(hbuf + tid * 4);
}

// ABLATION: epilogue only, x9 reps on garbage logits (NaN-safe: clamp chain
// maps NaN->b=0; projection addresses come from real per-row scalars).
// Stores to d_out only on the final rep (overwritten by fused_c51_k).
__global__ __launch_bounds__(512, 2) void abl_epi_k(
    const float* __restrict__ obs, const float* __restrict__ act,
    const float* __restrict__ rewards, const float* __restrict__ bootstrap,
    const float* __restrict__ discount, const float* __restrict__ q_support,
    const float* __restrict__ bias3, float* __restrict__ out)
{
  extern __shared__ char smem[];
  char* hbuf = smem;
  char* xbuf = smem + 65536;
  char* wbase = smem + 81920;
  const int tid = threadIdx.x;
  const int lane = tid & 63;
  const int w = tid >> 6;
  const long rowBase = (long)blockIdx.x * 64;

  stage_x(obs, act, xbuf, rowBase, tid);
  __syncthreads();
  #pragma unroll 1
  for (int rep = 0; rep < 9; ++rep) {
    asm volatile("" ::: "memory");
    run_epilogue(hbuf, (float*)wbase, rewards, bootstrap, discount, q_support,
                 bias3, out, rowBase, w, lane, rep == 8);
  }
}

extern "C" void kernel_launch(void* const* d_in, const int* in_sizes, int n_in,
                              void* d_out, int out_size, void* d_ws, size_t ws_size,
                              hipStream_t stream) {
  (void)n_in; (void)out_size; (void)ws_size;
  const float* obs       = (const float*)d_in[0];
  const float* actions   = (const float*)d_in[1];
  const float* rewards   = (const float*)d_in[2];
  const float* bootstrap = (const float*)d_in[3];
  const float* discount  = (const float*)d_in[4];
  const float* q_support = (const float*)d_in[5];
  const float* W1 = (const float*)d_in[6];
  const float* b1 = (const float*)d_in[7];
  const float* W2 = (const float*)d_in[8];
  const float* b2 = (const float*)d_in[9];
  const float* W3 = (const float*)d_in[10];
  const float* b3 = (const float*)d_in[11];
  float* out = (float*)d_out;
  f16* ws = (f16*)d_ws;
  const int B = in_sizes[2];

  hipLaunchKernelGGL(convert_weights_k, dim3(1792), dim3(256), 0, stream,
                     W1, W2, W3, ws);

  const int LDS_BYTES = 147456;  // 144 KB
  hipFuncSetAttribute(reinterpret_cast<const void*>(abl_gemm_k),
                      hipFuncAttributeMaxDynamicSharedMemorySize, LDS_BYTES);
  hipFuncSetAttribute(reinterpret_cast<const void*>(abl_epi_k),
                      hipFuncAttributeMaxDynamicSharedMemorySize, LDS_BYTES);
  hipFuncSetAttribute(reinterpret_cast<const void*>(fused_c51_k),
                      hipFuncAttributeMaxDynamicSharedMemorySize, LDS_BYTES);

  // Ablation probes (write scratch regions of d_out; fused kernel below
  // runs last and rewrites every d_out element with the real result).
  hipLaunchKernelGGL(abl_gemm_k, dim3(B / 64), dim3(512), LDS_BYTES, stream,
                     obs, actions, b1, b2, ws, out);
  hipLaunchKernelGGL(abl_epi_k, dim3(B / 64), dim3(512), LDS_BYTES, stream,
                     obs, actions, rewards, bootstrap, discount, q_support,
                     b3, out);

  hipLaunchKernelGGL(fused_c51_k, dim3(B / 64), dim3(512), LDS_BYTES, stream,
                     obs, actions, rewards, bootstrap, discount, q_support,
                     b1, b2, b3, ws, out);
}

// Round 6
// 500.038 us; speedup vs baseline: 13.8444x; 13.8444x over previous
//
#include <hip/hip_runtime.h>
#include <stdint.h>

typedef _Float16 f16;
typedef __attribute__((ext_vector_type(8))) _Float16 f16x8;
typedef __attribute__((ext_vector_type(4))) _Float16 f16x4;
typedef __attribute__((ext_vector_type(4))) float f32x4;

// Tiled weight layout in ws (f16 elems), K-tile = 32, tiles n-major [n][32]:
// W1: 4  tiles of [512][32] @ WS_W1; W2: 16 tiles of [512][32] @ WS_W2;
// W3: 16 tiles of [256][32] @ WS_W3 (n>=251 zeroed).
#define WS_W1 0
#define WS_W2 65536
#define WS_W3 327680

__global__ __launch_bounds__(256) void convert_weights_k(
    const float* __restrict__ W1, const float* __restrict__ W2,
    const float* __restrict__ W3, f16* __restrict__ ws)
{
  int idx = blockIdx.x * 256 + threadIdx.x;
  if (idx < 65536) {
    int kt = idx >> 14, r = idx & 16383, n = r >> 5, kk = r & 31;
    ws[WS_W1 + idx] = (f16)W1[(kt * 32 + kk) * 512 + n];
  } else if (idx < 327680) {
    int i = idx - 65536;
    int kt = i >> 14, r = i & 16383, n = r >> 5, kk = r & 31;
    ws[WS_W2 + i] = (f16)W2[(kt * 32 + kk) * 512 + n];
  } else if (idx < 458752) {
    int i = idx - 327680;
    int kt = i >> 13, r = i & 8191, n = r >> 5, kk = r & 31;
    ws[WS_W3 + i] = (n < 251) ? (f16)W3[(kt * 32 + kk) * 251 + n] : (f16)0.0f;
  }
}

__device__ __forceinline__ void gld16(char* lds, const char* g) {
  __builtin_amdgcn_global_load_lds(
      (const __attribute__((address_space(1))) uint32_t*)g,
      (__attribute__((address_space(3))) uint32_t*)lds, 16, 0, 0);
}

__device__ __forceinline__ f16x8 lds_ld8(const char* base, int m, int strideB, int kb) {
  return *(const f16x8*)(base + m * strideB + (kb ^ ((m & 7) << 4)));
}

// --------------------------- GEMM building blocks ---------------------------
// Barrier-free per-wave weight streaming (round-4 structure, verbatim).
template<int NT>
__device__ __forceinline__ void mlp_stage(
    const f16* __restrict__ wsrc, int ktiles, int tileB,
    char* slot0, char* slot1,
    const char* __restrict__ src, int srcStride,
    f32x4 acc[4][NT], int w, int lane, int l15, int lh)
{
  const char* gsrc = (const char*)wsrc + w * (NT * 1024) + lane * 16;
  #pragma unroll
  for (int r = 0; r < NT; ++r) gld16(slot0 + r * 1024, gsrc + r * 1024);
  #pragma unroll 1
  for (int kt = 0; kt < ktiles; ++kt) {
    char* cur = (kt & 1) ? slot1 : slot0;
    char* nxt = (kt & 1) ? slot0 : slot1;
    if (kt + 1 < ktiles) {
      const char* g = gsrc + (size_t)(kt + 1) * tileB;
      __builtin_amdgcn_sched_barrier(0);
      #pragma unroll
      for (int r = 0; r < NT; ++r) gld16(nxt + r * 1024, g + r * 1024);
      asm volatile("s_waitcnt vmcnt(%0)" :: "n"(NT) : "memory");
    } else {
      asm volatile("s_waitcnt vmcnt(0)" ::: "memory");
    }
    __builtin_amdgcn_sched_barrier(0);
    f16x8 a[NT];
    #pragma unroll
    for (int nt = 0; nt < NT; ++nt)
      a[nt] = *(const f16x8*)(cur + (nt * 16 + l15) * 64 + lh * 16);
    __builtin_amdgcn_s_setprio(1);
    #pragma unroll
    for (int mh = 0; mh < 4; ++mh) {
      f16x8 b = lds_ld8(src, mh * 16 + l15, srcStride, kt * 64 + lh * 16);
      #pragma unroll
      for (int nt = 0; nt < NT; ++nt)
        acc[mh][nt] = __builtin_amdgcn_mfma_f32_16x16x32_f16(a[nt], b, acc[mh][nt], 0, 0, 0);
    }
    __builtin_amdgcn_s_setprio(0);
  }
}

template<int NT>
__device__ __forceinline__ void store_act(
    f32x4 acc[4][NT], char* hbuf, const float* __restrict__ bias,
    int w, int l15, int lh)
{
  #pragma unroll
  for (int nt = 0; nt < NT; ++nt) {
    int ncol = w * (NT * 16) + nt * 16 + lh * 4;
    f32x4 bv = *(const f32x4*)(bias + ncol);
    #pragma unroll
    for (int mh = 0; mh < 4; ++mh) {
      int m = mh * 16 + l15;
      f16x4 hv;
      #pragma unroll
      for (int r = 0; r < 4; ++r) {
        float v = acc[mh][nt][r] + bv[r];
        hv[r] = (f16)(v > 0.f ? v : 0.01f * v);
      }
      *(f16x4*)(hbuf + m * 1024 + ((ncol * 2) ^ ((m & 7) << 4))) = hv;
    }
  }
}

// Stage-3 store: TRANSPOSED logits lgT[atom][row] (f32), + b3 folded in,
// atoms >= 251 padded with -3e38 (excluded from softmax automatically).
__device__ __forceinline__ void store_logits_T(
    f32x4 acc[4][2], float* lgT, const float* __restrict__ bias3,
    int w, int l15, int lh)
{
  #pragma unroll
  for (int nt = 0; nt < 2; ++nt) {
    int abase = w * 32 + nt * 16 + lh * 4;     // atom index for r=0..3
    float bv[4];
    #pragma unroll
    for (int r = 0; r < 4; ++r) {
      int a = abase + r;
      bv[r] = (a < 251) ? bias3[a] : 0.f;
    }
    #pragma unroll
    for (int mh = 0; mh < 4; ++mh) {
      int m = mh * 16 + l15;
      #pragma unroll
      for (int r = 0; r < 4; ++r) {
        int a = abase + r;
        float val = (a < 251) ? (acc[mh][nt][r] + bv[r]) : -3.0e38f;
        lgT[a * 64 + m] = val;
      }
    }
  }
}

__device__ __forceinline__ void stage_x(
    const float* __restrict__ obs, const float* __restrict__ act,
    char* xbuf, long rowBase, int tid)
{
  #pragma unroll
  for (int i = 0; i < 2; ++i) {
    int chunk = tid + i * 512;
    int m = chunk >> 4, g = chunk & 15;
    long row = rowBase + m;
    const float* src = (g < 12) ? (obs + row * 96 + g * 8)
                                : (act + row * 32 + (g - 12) * 8);
    float4 lo = ((const float4*)src)[0];
    float4 hi = ((const float4*)src)[1];
    f16x8 v;
    v[0] = (f16)lo.x; v[1] = (f16)lo.y; v[2] = (f16)lo.z; v[3] = (f16)lo.w;
    v[4] = (f16)hi.x; v[5] = (f16)hi.y; v[6] = (f16)hi.z; v[7] = (f16)hi.w;
    *(f16x8*)(xbuf + m * 256 + ((g * 16) ^ ((m & 7) << 4))) = v;
  }
}

// All 3 GEMM stages; stage 3 ends with the transposed logit store.
__device__ __forceinline__ void run_gemms(
    const f16* __restrict__ ws, char* xbuf, char* hbuf,
    char* slot0, char* slot1,
    const float* __restrict__ bias1, const float* __restrict__ bias2,
    const float* __restrict__ bias3,
    int w, int lane, int l15, int lh)
{
  {
    f32x4 acc[4][4];
    #pragma unroll
    for (int mh = 0; mh < 4; ++mh)
      #pragma unroll
      for (int nt = 0; nt < 4; ++nt) acc[mh][nt] = f32x4{0.f, 0.f, 0.f, 0.f};
    mlp_stage<4>(ws + WS_W1, 4, 32768, slot0, slot1, xbuf, 256, acc, w, lane, l15, lh);
    store_act<4>(acc, hbuf, bias1, w, l15, lh);
  }
  __syncthreads();
  {
    f32x4 acc[4][4];
    #pragma unroll
    for (int mh = 0; mh < 4; ++mh)
      #pragma unroll
      for (int nt = 0; nt < 4; ++nt) acc[mh][nt] = f32x4{0.f, 0.f, 0.f, 0.f};
    mlp_stage<4>(ws + WS_W2, 16, 32768, slot0, slot1, hbuf, 1024, acc, w, lane, l15, lh);
    __syncthreads();   // all waves done reading h1
    store_act<4>(acc, hbuf, bias2, w, l15, lh);
  }
  __syncthreads();
  {
    f32x4 acc[4][2];
    #pragma unroll
    for (int mh = 0; mh < 4; ++mh)
      #pragma unroll
      for (int nt = 0; nt < 2; ++nt) acc[mh][nt] = f32x4{0.f, 0.f, 0.f, 0.f};
    mlp_stage<2>(ws + WS_W3, 16, 16384, slot0, slot1, hbuf, 1024, acc, w, lane, l15, lh);
    __syncthreads();   // all waves done reading h2
    store_logits_T(acc, (float*)hbuf, bias3, w, l15, lh);
  }
}

// ---------------------------------------------------------------------------
// Epilogue v2: lane-per-row softmax + projection. Wave w owns atoms
// [w*32, w*32+32); lane = row. No cross-lane shuffles; 4 barriers total.
// prT[bin][row] with row^(bin&31) XOR -> bank-spread atomics & reads.
// ---------------------------------------------------------------------------
__device__ __forceinline__ void run_epilogue_v2(
    const float* __restrict__ lgT, float* __restrict__ prT,
    float* __restrict__ pmax, float* __restrict__ psum,
    const float* __restrict__ rewards, const float* __restrict__ bootstrap,
    const float* __restrict__ discount, const float* __restrict__ q_support,
    float* __restrict__ out, long rowBase, int w, int lane, int tid)
{
  // zero prT (64KB, all threads) — completes before atomics (2 barriers later)
  #pragma unroll
  for (int z = 0; z < 8; ++z)
    *(f32x4*)((char*)prT + (z * 512 + tid) * 16) = f32x4{0.f, 0.f, 0.f, 0.f};

  const int a0 = w * 32;
  // pass 1: 32 atoms of row `lane` into registers; per-wave partial max
  float e[32];
  #pragma unroll
  for (int i = 0; i < 32; ++i) e[i] = lgT[(a0 + i) * 64 + lane];
  float m0 = e[0], m1 = e[1], m2 = e[2], m3 = e[3];
  #pragma unroll
  for (int i = 4; i < 32; i += 4) {
    m0 = fmaxf(m0, e[i]);     m1 = fmaxf(m1, e[i + 1]);
    m2 = fmaxf(m2, e[i + 2]); m3 = fmaxf(m3, e[i + 3]);
  }
  pmax[w * 64 + lane] = fmaxf(fmaxf(m0, m1), fmaxf(m2, m3));
  float rw = rewards[rowBase + lane];
  float bd = __fmul_rn(bootstrap[rowBase + lane], discount[rowBase + lane]);
  __syncthreads();

  // pass 2: global row max; exp in registers; per-wave partial sum
  float mx = pmax[lane];
  #pragma unroll
  for (int ww = 1; ww < 8; ++ww) mx = fmaxf(mx, pmax[ww * 64 + lane]);
  float s0 = 0.f, s1 = 0.f, s2 = 0.f, s3 = 0.f;
  #pragma unroll
  for (int i = 0; i < 32; i += 4) {
    e[i]     = __expf(e[i]     - mx); s0 += e[i];
    e[i + 1] = __expf(e[i + 1] - mx); s1 += e[i + 1];
    e[i + 2] = __expf(e[i + 2] - mx); s2 += e[i + 2];
    e[i + 3] = __expf(e[i + 3] - mx); s3 += e[i + 3];
  }
  psum[w * 64 + lane] = (s0 + s1) + (s2 + s3);
  __syncthreads();

  float tot = psum[lane];
  #pragma unroll
  for (int ww = 1; ww < 8; ++ww) tot += psum[ww * 64 + lane];
  float inv = 1.f / tot;

  // pass 3: projection scatter (exact reference fp chain per element)
  #pragma unroll
  for (int i = 0; i < 32; ++i) {
    int a = a0 + i;
    if (a < 251) {                       // wave-uniform guard
      float p = e[i] * inv;
      float zc = q_support[a];
      float tz = __fadd_rn(rw, __fmul_rn(bd, zc));
      tz = fminf(fmaxf(tz, -100.f), 100.f);
      float b = __fdiv_rn(__fadd_rn(tz, 100.f), 0.8f);
      float lf = floorf(b), uf = ceilf(b);
      int li = (int)lf, ui = (int)uf;
      bool eq = (li == ui);
      int li2 = li - ((eq && (ui > 0)) ? 1 : 0);
      int ui2 = ui + ((eq && (li < 250)) ? 1 : 0);
      atomicAdd(&prT[li2 * 64 + (lane ^ (li2 & 31))], p * ((float)ui2 - b));
      atomicAdd(&prT[ui2 * 64 + (lane ^ (ui2 & 31))], p * (b - (float)li2));
    }
  }
  __syncthreads();

  // output: fully coalesced global stores; bank-spread LDS reads
  for (unsigned i = tid; i < 64u * 251u; i += 512u) {
    unsigned row = i / 251u;
    unsigned c = i - row * 251u;
    out[rowBase * 251 + i] = prT[c * 64 + (row ^ (c & 31))];
  }
}

// ------------------------------- fused kernel -------------------------------
// LDS: hbuf 64KB (x->h1->h2->lgT) | xbuf 16KB (x; then pmax/psum) |
//      wslots 64KB (weight dbuf; then prT). 144KB total.
__global__ __launch_bounds__(512, 2) void fused_c51_k(
    const float* __restrict__ obs, const float* __restrict__ act,
    const float* __restrict__ rewards, const float* __restrict__ bootstrap,
    const float* __restrict__ discount, const float* __restrict__ q_support,
    const float* __restrict__ bias1, const float* __restrict__ bias2,
    const float* __restrict__ bias3, const f16* __restrict__ ws,
    float* __restrict__ out)
{
  extern __shared__ char smem[];
  char* hbuf = smem;
  char* xbuf = smem + 65536;
  char* wbase = smem + 81920;
  float* pmax = (float*)(smem + 65536);
  float* psum = (float*)(smem + 65536 + 2048);
  float* prT  = (float*)wbase;

  const int tid = threadIdx.x;
  const int lane = tid & 63;
  const int w = tid >> 6;
  const int l15 = lane & 15;
  const int lh = lane >> 4;
  const long rowBase = (long)blockIdx.x * 64;
  char* slot0 = wbase + w * 8192;
  char* slot1 = slot0 + 4096;

  stage_x(obs, act, xbuf, rowBase, tid);
  __syncthreads();
  run_gemms(ws, xbuf, hbuf, slot0, slot1, bias1, bias2, bias3, w, lane, l15, lh);
  __syncthreads();   // lgT visible to all waves
  run_epilogue_v2((const float*)hbuf, prT, pmax, psum,
                  rewards, bootstrap, discount, q_support,
                  out, rowBase, w, lane, tid);
}

extern "C" void kernel_launch(void* const* d_in, const int* in_sizes, int n_in,
                              void* d_out, int out_size, void* d_ws, size_t ws_size,
                              hipStream_t stream) {
  (void)n_in; (void)out_size; (void)ws_size;
  const float* obs       = (const float*)d_in[0];
  const float* actions   = (const float*)d_in[1];
  const float* rewards   = (const float*)d_in[2];
  const float* bootstrap = (const float*)d_in[3];
  const float* discount  = (const float*)d_in[4];
  const float* q_support = (const float*)d_in[5];
  const float* W1 = (const float*)d_in[6];
  const float* b1 = (const float*)d_in[7];
  const float* W2 = (const float*)d_in[8];
  const float* b2 = (const float*)d_in[9];
  const float* W3 = (const float*)d_in[10];
  const float* b3 = (const float*)d_in[11];
  float* out = (float*)d_out;
  f16* ws = (f16*)d_ws;
  const int B = in_sizes[2];

  hipLaunchKernelGGL(convert_weights_k, dim3(1792), dim3(256), 0, stream,
                     W1, W2, W3, ws);

  const int LDS_BYTES = 147456;  // 144 KB
  hipFuncSetAttribute(reinterpret_cast<const void*>(fused_c51_k),
                      hipFuncAttributeMaxDynamicSharedMemorySize, LDS_BYTES);
  hipLaunchKernelGGL(fused_c51_k, dim3(B / 64), dim3(512), LDS_BYTES, stream,
                     obs, actions, rewards, bootstrap, discount, q_support,
                     b1, b2, b3, ws, out);
}